// Round 2
// baseline (376.944 us; speedup 1.0000x reference)
//
#include <hip/hip_runtime.h>
#include <hip/hip_bf16.h>
#include <stdint.h>

#define NSEQ 4096
#define DDIM 768
#define NB   4
#define NTRI 528          // 32*33/2 lower-tri 128-blocks per batch
#define BLKE 16384        // 128*128

typedef short short8 __attribute__((ext_vector_type(8)));
typedef float f32x16 __attribute__((ext_vector_type(16)));

__device__ __forceinline__ unsigned short f2bf(float f) {
    unsigned int u = __float_as_uint(f);
    u += 0x7fffu + ((u >> 16) & 1u);
    return (unsigned short)(u >> 16);
}
__device__ __forceinline__ short8 cvt8(const float* __restrict__ p) {
    float4 x = *(const float4*)p;
    float4 y = *(const float4*)(p + 4);
    union { short8 s; __hip_bfloat162 h[4]; } u;
    u.h[0] = __float22bfloat162_rn(make_float2(x.x, x.y));
    u.h[1] = __float22bfloat162_rn(make_float2(x.z, x.w));
    u.h[2] = __float22bfloat162_rn(make_float2(y.x, y.y));
    u.h[3] = __float22bfloat162_rn(make_float2(y.z, y.w));
    return u.s;
}

// async global->LDS, 16B per lane (global_load_lds_dwordx4)
typedef const __attribute__((address_space(1))) unsigned int ga_u32;
typedef __attribute__((address_space(3))) unsigned int ls_u32;
__device__ __forceinline__ void gload_lds16(const void* g, void* l) {
    __builtin_amdgcn_global_load_lds((ga_u32*)(uintptr_t)g, (ls_u32*)(uintptr_t)l, 16, 0, 0);
}

// ---------------------------------------------------------------------------
// XOR-swizzled LDS tile: stored 16B chunk p of row r holds global chunk
// p ^ (r&7) ^ ((r>>3)&3). Swizzle applied on the GLOBAL source column so the
// LDS dest stays wave-uniform base + lane*16 (global_load_lds requirement).
// 256-thread version (128 rows x 64 cols) — used by gemm_pv.
// ---------------------------------------------------------------------------
__device__ __forceinline__ void stage_tile(const unsigned short* gbase, int stride,
                                           unsigned short* lds, int tid) {
    const int lane = tid & 63, wv = tid >> 6;
    const int r8  = lane >> 3;
    const int cl  = (lane & 7) * 8;          // LDS dest col group (lane*16B)
#pragma unroll
    for (int t = 0; t < 4; ++t) {
        const int row = wv * 32 + t * 8 + r8;
        const int csw = (((lane & 7) ^ r8 ^ t) & 7) * 8;   // swizzled global col
        gload_lds16(gbase + (size_t)row * stride + csw, lds + row * 64 + cl);
    }
}

// 512-thread version: 256 rows x 64 cols, 4 shots of 64 rows.
// row = s*64 + wv*8 + r8  ->  row&7 = r8, (row>>3)&3 = wv&3 (shot-invariant).
__device__ __forceinline__ void stage_tile8(const unsigned short* gbase, int stride,
                                            unsigned short* lds, int tid) {
    const int lane = tid & 63, wv = tid >> 6;          // wv 0..7
    const int r8  = lane >> 3;
    const int cl  = (lane & 7) * 8;
    const int rb  = wv * 8 + r8;                       // 0..63
    const int csw = (((lane & 7) ^ r8 ^ (wv & 3)) & 7) * 8;
#pragma unroll
    for (int s = 0; s < 4; ++s) {
        const int row = s * 64 + rb;
        gload_lds16(gbase + (size_t)row * stride + csw, lds + row * 64 + cl);
    }
}

// ---------------------------------------------------------------------------
// 256-thread BK=64 compute step (gemm_pv): 4 k16-chunks x (4 ds_read_b128 +
// 4 MFMA). Wave tile 64x64 = 2x2 of 32x32.
// ---------------------------------------------------------------------------
__device__ __forceinline__ void mma_tiles(const unsigned short* As, const unsigned short* Bs,
                                          f32x16 acc[2][2], int wm, int wn, int lane) {
    const int r32 = lane & 31;
    const int hi  = lane >> 5;
    const int sw  = (lane & 7) ^ ((lane >> 3) & 3);
#pragma unroll
    for (int c = 0; c < 4; ++c) {
        const int chunk = (((c * 2 + hi) ^ sw) & 7) * 8;
        short8 af[2], bg[2];
#pragma unroll
        for (int mt = 0; mt < 2; ++mt)
            af[mt] = *(const short8*)(As + (wm * 64 + mt * 32 + r32) * 64 + chunk);
#pragma unroll
        for (int nt = 0; nt < 2; ++nt)
            bg[nt] = *(const short8*)(Bs + (wn * 64 + nt * 32 + r32) * 64 + chunk);
#pragma unroll
        for (int mt = 0; mt < 2; ++mt)
#pragma unroll
            for (int nt = 0; nt < 2; ++nt)
                acc[mt][nt] = __builtin_amdgcn_mfma_f32_32x32x16_bf16(af[mt], bg[nt], acc[mt][nt], 0, 0, 0);
    }
}

// C/D layout (m74/m101-verified): col = lane&31, row = (reg&3)+8*(reg>>2)+4*(lane>>5)
__device__ __forceinline__ int crow(int reg, int hi) {
    return (reg & 3) + 8 * (reg >> 2) + 4 * hi;
}

// ---------------------------------------------------------------------------
// 512-thread / 8-wave (2M x 4N) group: one BK=64 K-tile, 4 sub-phases (one per
// mt quadrant). Per phase: ds_read subtile -> s_barrier -> lgkmcnt(0) ->
// setprio(1) -> 8 MFMA -> setprio(0). Staging for the OTHER LDS buffer is
// issued at phase 0 (~3.5 phases before its drain); one vmcnt(0)+barrier at
// group end. Race audit:
//  - stage targets buf(1-p), whose reads (previous group) were retired by each
//    wave's lgkmcnt(0) before its last MFMA, globally fenced by the previous
//    group-end barrier that precedes this call.
//  - reads of staged data occur only after this group's end vmcnt(0)+barrier.
// Per-wave tile 128x64: acc[4][2], B frags cached in regs across phases.
// ---------------------------------------------------------------------------
__device__ __forceinline__ void group_compute(
    const unsigned short* __restrict__ Asb, const unsigned short* __restrict__ Bsb,
    const unsigned short* a_src, const unsigned short* b_src, int stride,
    unsigned short* a_dst, unsigned short* b_dst, bool do_stage,
    f32x16 (&acc)[4][2], int wm, int wn, int lane, int tid)
{
    const int r32 = lane & 31, hi = lane >> 5;
    const int sw  = (lane & 7) ^ ((lane >> 3) & 3);

    if (do_stage) {
        stage_tile8(a_src, stride, a_dst, tid);
        stage_tile8(b_src, stride, b_dst, tid);
    }

    short8 bg[2][4];
    const unsigned short* Bw = Bsb + (size_t)(wn * 64 + r32) * 64;
#pragma unroll
    for (int c = 0; c < 4; ++c) {
        const int chunk = (((c * 2 + hi) ^ sw) & 7) * 8;
        bg[0][c] = *(const short8*)(Bw + chunk);
        bg[1][c] = *(const short8*)(Bw + 32 * 64 + chunk);
    }

#pragma unroll
    for (int mt = 0; mt < 4; ++mt) {
        short8 af[4];
        const unsigned short* Aw = Asb + (size_t)(wm * 128 + mt * 32 + r32) * 64;
#pragma unroll
        for (int c = 0; c < 4; ++c)
            af[c] = *(const short8*)(Aw + (((c * 2 + hi) ^ sw) & 7) * 8);
        __builtin_amdgcn_s_barrier();
        asm volatile("s_waitcnt lgkmcnt(0)" ::: "memory");
        __builtin_amdgcn_sched_barrier(0);
        __builtin_amdgcn_s_setprio(1);
#pragma unroll
        for (int c = 0; c < 4; ++c) {
            acc[mt][0] = __builtin_amdgcn_mfma_f32_32x32x16_bf16(af[c], bg[0][c], acc[mt][0], 0, 0, 0);
            acc[mt][1] = __builtin_amdgcn_mfma_f32_32x32x16_bf16(af[c], bg[1][c], acc[mt][1], 0, 0, 0);
        }
        __builtin_amdgcn_s_setprio(0);
    }
    asm volatile("s_waitcnt vmcnt(0)" ::: "memory");   // drain stage issued at phase 0
    __builtin_amdgcn_s_barrier();
}

// ---------------------------------------------------------------------------
// fp32 -> bf16 convert: X (6144 blocks), Wq/Wk/Wv (288 blocks each).
// Extra 16 blocks zero the row-sum accumulator L; block 0 zeroes the counter.
// ---------------------------------------------------------------------------
__global__ __launch_bounds__(256)
void convert_kernel(const float* __restrict__ X, const float* __restrict__ Wq,
                    const float* __restrict__ Wk, const float* __restrict__ Wv,
                    unsigned short* __restrict__ Xb, unsigned short* __restrict__ Wb,
                    float* __restrict__ L, unsigned int* __restrict__ counter)
{
    const int bid = blockIdx.x;
    if (bid == 0 && threadIdx.x == 0) *counter = 0u;
    if (bid >= 7008) {                      // zero L: 16 blocks x 1024 floats
        const int idx = (bid - 7008) * 1024 + threadIdx.x * 4;
        *(float4*)(L + idx) = make_float4(0.f, 0.f, 0.f, 0.f);
        return;
    }
    const float* src; unsigned short* dst; size_t off;
    if (bid < 6144) { src = X; dst = Xb; off = (size_t)bid * 2048; }
    else {
        const int wbid = bid - 6144;
        const int wi = wbid / 288;
        src = (wi == 0) ? Wq : ((wi == 1) ? Wk : Wv);
        dst = Wb + (size_t)wi * (DDIM * DDIM);
        off = (size_t)(wbid - wi * 288) * 2048;
    }
    const size_t i = off + (size_t)threadIdx.x * 8;
    *(short8*)(dst + i) = cvt8(src + i);
}

// ---------------------------------------------------------------------------
// QKV: C = Xb * Wb^T per weight. 256x256 tile, BK=64, 512 thr, 8-wave 2Mx4N,
// phase-interleaved group schedule. grid (64,3,3).
// ---------------------------------------------------------------------------
__global__ __launch_bounds__(512, 2)
void qkv_gemm(const unsigned short* __restrict__ Xb, const unsigned short* __restrict__ Wb,
              unsigned short* __restrict__ Qb, unsigned short* __restrict__ Kb,
              unsigned short* __restrict__ Vtb)
{
    const int tid = threadIdx.x, lane = tid & 63, wv = tid >> 6;
    const int r32 = lane & 31, hi = lane >> 5, wm = wv >> 2, wn = wv & 3;
    const int m0 = blockIdx.x * 256, n0 = blockIdx.y * 256, widx = blockIdx.z;
    const unsigned short* A = Xb + (size_t)m0 * DDIM;
    const unsigned short* B = Wb + (size_t)widx * (DDIM * DDIM) + (size_t)n0 * DDIM;

    __shared__ __align__(16) unsigned short As[2][256 * 64];
    __shared__ __align__(16) unsigned short Bs[2][256 * 64];

    f32x16 acc[4][2] = {};

    stage_tile8(A, DDIM, As[0], tid);
    stage_tile8(B, DDIM, Bs[0], tid);
    asm volatile("s_waitcnt vmcnt(0)" ::: "memory");
    __builtin_amdgcn_s_barrier();

    for (int t = 0; t < 12; ++t) {
        const int p = t & 1;
        group_compute(As[p], Bs[p],
                      A + (t + 1) * 64, B + (t + 1) * 64, DDIM,
                      As[1 - p], Bs[1 - p], t + 1 < 12,
                      acc, wm, wn, lane, tid);
    }

    const int m_base = m0 + wm * 128, o_base = n0 + wn * 64;
    if (widx < 2) {
        unsigned short* dst = (widx == 0) ? Qb : Kb;
#pragma unroll
        for (int mt = 0; mt < 4; ++mt)
#pragma unroll
            for (int nt = 0; nt < 2; ++nt)
#pragma unroll
                for (int reg = 0; reg < 16; ++reg)
                    dst[(size_t)(m_base + mt * 32 + crow(reg, hi)) * DDIM +
                        (o_base + nt * 32 + r32)] = f2bf(acc[mt][nt][reg]);
    } else {
        // Vt[b][o][n]: regs b4*4+0..3 are rows n..n+3 -> ushort4 pack
        const int bb = m0 >> 12;
        const int n_seq0 = (m0 & (NSEQ - 1)) + wm * 128;
#pragma unroll
        for (int mt = 0; mt < 4; ++mt)
#pragma unroll
            for (int nt = 0; nt < 2; ++nt) {
                const int o = o_base + nt * 32 + r32;
#pragma unroll
                for (int b4 = 0; b4 < 4; ++b4) {
                    ushort4 pk;
                    pk.x = f2bf(acc[mt][nt][b4 * 4 + 0]);
                    pk.y = f2bf(acc[mt][nt][b4 * 4 + 1]);
                    pk.z = f2bf(acc[mt][nt][b4 * 4 + 2]);
                    pk.w = f2bf(acc[mt][nt][b4 * 4 + 3]);
                    const int n = n_seq0 + mt * 32 + b4 * 8 + hi * 4;
                    *(ushort4*)(Vtb + ((size_t)(bb * DDIM + o)) * NSEQ + n) = pk;
                }
            }
    }
}

// ---------------------------------------------------------------------------
// S-pass at 256x256, softmax fused in epilogue. Sbuf keeps the verified
// 128-block tri layout: each wave's 128 rows/cols lie in exactly one
// 128-block (qb128 = 2*qsb+wm, kb128 = 2*ksb+(wn>>1)); waves with
// kb128>qb128 (upper half of diagonal superblock) store nothing.
// grid (136, 4), 512 thr.
// ---------------------------------------------------------------------------
__global__ __launch_bounds__(512, 2)
void gemm_s(const unsigned short* __restrict__ Qb, const unsigned short* __restrict__ Kb,
            unsigned short* __restrict__ Sbuf, float* __restrict__ L)
{
    const float c2 = 0.05205877475f;  // log2(e)/sqrt(768)
    const int tid = threadIdx.x, lane = tid & 63, wv = tid >> 6;
    const int r32 = lane & 31, hi = lane >> 5, wm = wv >> 2, wn = wv & 3;
    const int idx = blockIdx.x, bb = blockIdx.y;
    int qsb = (int)((sqrtf(8.f * idx + 1.f) - 1.f) * 0.5f);
    while ((qsb + 1) * (qsb + 2) / 2 <= idx) ++qsb;
    while (qsb * (qsb + 1) / 2 > idx) --qsb;
    const int ksb = idx - qsb * (qsb + 1) / 2;

    const unsigned short* A = Qb + ((size_t)bb * NSEQ + qsb * 256) * DDIM;
    const unsigned short* B = Kb + ((size_t)bb * NSEQ + ksb * 256) * DDIM;

    __shared__ __align__(16) unsigned short As[2][256 * 64];
    __shared__ __align__(16) unsigned short Bs[2][256 * 64];

    f32x16 acc[4][2] = {};

    stage_tile8(A, DDIM, As[0], tid);
    stage_tile8(B, DDIM, Bs[0], tid);
    asm volatile("s_waitcnt vmcnt(0)" ::: "memory");
    __builtin_amdgcn_s_barrier();

    for (int t = 0; t < 12; ++t) {
        const int p = t & 1;
        group_compute(As[p], Bs[p],
                      A + (t + 1) * 64, B + (t + 1) * 64, DDIM,
                      As[1 - p], Bs[1 - p], t + 1 < 12,
                      acc, wm, wn, lane, tid);
    }

    const int qb128 = qsb * 2 + wm;
    const int kb128 = ksb * 2 + (wn >> 1);
    if (kb128 > qb128) return;              // upper half of diag superblock: no slot
    unsigned short* Sblk = Sbuf + ((size_t)(bb * NTRI + qb128 * (qb128 + 1) / 2 + kb128)) * BLKE;
    float* Lrow = L + (size_t)bb * NSEQ + (qb128 << 7);
    const int coff = (wn & 1) * 64;
    const bool diag = (qb128 == kb128);
#pragma unroll
    for (int mt = 0; mt < 4; ++mt)
#pragma unroll
        for (int rp = 0; rp < 8; ++rp) {            // reg pair: rows row0, row0+1
            const int reg0 = rp * 2, reg1 = reg0 + 1;
            const int row0 = mt * 32 + crow(reg0, hi);   // 128-local
            const int row1 = row0 + 1;
            float vs0 = 0.f, vs1 = 0.f;
#pragma unroll
            for (int nt = 0; nt < 2; ++nt) {
                const int col = coff + nt * 32 + r32;    // 128-local
                float e0 = (diag && col > row0) ? 0.f : exp2f(acc[mt][nt][reg0] * c2);
                float e1 = (diag && col > row1) ? 0.f : exp2f(acc[mt][nt][reg1] * c2);
                union { __hip_bfloat162 h; ushort2 u; } cv;
                cv.h = __float22bfloat162_rn(make_float2(e0, e1));
                Sblk[row0 * 128 + col] = cv.u.x;
                Sblk[row1 * 128 + col] = cv.u.y;
                vs0 += e0;
                vs1 += e1;
            }
#pragma unroll
            for (int s = 1; s < 32; s <<= 1) {
                vs0 += __shfl_xor(vs0, s);
                vs1 += __shfl_xor(vs1, s);
            }
            if (r32 == 0) {
                atomicAdd(&Lrow[row0], vs0);
                atomicAdd(&Lrow[row1], vs1);
            }
        }
}

// ---------------------------------------------------------------------------
// O = P' V * (1/L[q]). Persistent queue, items (qb desc, b, ob). grid 512.
// (unchanged from verified baseline)
// ---------------------------------------------------------------------------
__global__ __launch_bounds__(256)
void gemm_pv(const unsigned short* __restrict__ P, const unsigned short* __restrict__ Vt,
             const float* __restrict__ L, float* __restrict__ Out,
             unsigned int* __restrict__ counter)
{
    const int tid = threadIdx.x, lane = tid & 63, wv = tid >> 6;
    const int r32 = lane & 31, hi = lane >> 5, wm = wv >> 1, wn = wv & 1;

    __shared__ __align__(16) unsigned short As[128 * 64];
    __shared__ __align__(16) unsigned short Bs[128 * 64];
    __shared__ float Linv[128];
    __shared__ unsigned int item_s;

    for (;;) {
        if (tid == 0) item_s = atomicAdd(counter, 1u);
        __syncthreads();
        const unsigned int item = item_s;
        if (item >= 768u) return;

        const int t = (int)(item / 24u);
        const int qb = 31 - t;
        const int rem = (int)(item - (unsigned)t * 24u);
        const int bb = rem / 6, ob = rem % 6;
        const size_t triq = (size_t)qb * (qb + 1) / 2;
        const unsigned short* Pbat = P + (size_t)bb * NTRI * BLKE;
        const unsigned short* Bbase = Vt + ((size_t)(bb * DDIM + ob * 128)) * NSEQ;
        const int niter = (qb + 1) * 2;

        if (tid < 128) Linv[tid] = 1.0f / L[(size_t)bb * NSEQ + qb * 128 + tid];

        f32x16 acc[2][2] = {};

        for (int it = 0; it < niter; ++it) {
            const int k0 = it * 64;
            const int kblk = k0 >> 7, cb = k0 & 64;
            stage_tile(Pbat + (triq + kblk) * BLKE + cb, 128, As, tid);
            stage_tile(Bbase + k0, NSEQ, Bs, tid);
            __syncthreads();
            mma_tiles(As, Bs, acc, wm, wn, lane);
            __syncthreads();
        }

        const int o_base = ob * 128 + wn * 64;
#pragma unroll
        for (int mt = 0; mt < 2; ++mt)
#pragma unroll
            for (int nt = 0; nt < 2; ++nt)
#pragma unroll
                for (int reg = 0; reg < 16; ++reg) {
                    const int rl = wm * 64 + mt * 32 + crow(reg, hi);
                    const int q = qb * 128 + rl;
                    Out[((size_t)(bb * NSEQ + q)) * DDIM + (o_base + nt * 32 + r32)] =
                        acc[mt][nt][reg] * Linv[rl];
                }
        // Linv rewrite for next item is fenced by the top-of-loop __syncthreads
    }
}

extern "C" void kernel_launch(void* const* d_in, const int* in_sizes, int n_in,
                              void* d_out, int out_size, void* d_ws, size_t ws_size,
                              hipStream_t stream)
{
    const float* X  = (const float*)d_in[0];
    const float* Wq = (const float*)d_in[1];
    const float* Wk = (const float*)d_in[2];
    const float* Wv = (const float*)d_in[3];
    float* Out = (float*)d_out;

    const size_t E = (size_t)NB * NSEQ * DDIM;  // 12,582,912
    char* ws = (char*)d_ws;
    unsigned short* Qb  = (unsigned short*)ws;          // E bf16
    unsigned short* Kb  = Qb + E;
    unsigned short* Vtb = Kb + E;
    unsigned short* Sbuf = Vtb + E;                     // 34,603,008 bf16 (overlay region)
    unsigned short* Xb  = Sbuf;                         // dead before Sbuf is written
    unsigned short* Wb  = Xb + E;                       // 3*589824 bf16 (also dead)
    float* L = (float*)(ws + 3 * E * 2 + (size_t)NB * NTRI * BLKE * 2);  // 16384 f32
    unsigned int* counter = (unsigned int*)(L + (size_t)NB * NSEQ);
    // ws required: 75,497,472 + 69,206,016 + 65,536 + 4 ≈ 144.77 MB

    convert_kernel<<<7024, 256, 0, stream>>>(X, Wq, Wk, Wv, Xb, Wb, L, counter);
    qkv_gemm<<<dim3(64, 3, 3), 512, 0, stream>>>(Xb, Wb, Qb, Kb, Vtb);
    gemm_s<<<dim3(136, NB), 512, 0, stream>>>(Qb, Kb, Sbuf, L);
    gemm_pv<<<512, 256, 0, stream>>>(Sbuf, Vtb, L, Out, counter);
}